// Round 1
// baseline (548.257 us; speedup 1.0000x reference)
//
#include <hip/hip_runtime.h>
#include <stdint.h>

// ---------------- types ----------------
using i32x4 = __attribute__((ext_vector_type(4))) int;
using f32x4 = __attribute__((ext_vector_type(4))) float;
using f16x4 = __attribute__((ext_vector_type(4))) _Float16;

#define M_TOK 8192
#define N_EMB 1024
#define D_FF  4096

__device__ __forceinline__ void async_lds16(void* lds, const void* g) {
  __builtin_amdgcn_global_load_lds(
      (const __attribute__((address_space(1))) void*)g,
      (__attribute__((address_space(3))) void*)lds, 16, 0, 0);
}

// ---------------- tiny init ----------------
__global__ void zero_slots_k(unsigned* s) {
  if (threadIdx.x < 16) s[threadIdx.x] = 0u;
}

// ---------------- global absmax (float bits atomicMax, order-independent) ----------------
__global__ void absmax_k(const float* __restrict__ p, long n, unsigned* __restrict__ slot) {
  long i = ((long)blockIdx.x * blockDim.x + threadIdx.x) * 4;
  long stride = (long)gridDim.x * blockDim.x * 4;
  float m = 0.f;
  for (; i < n; i += stride) {
    float4 v = *(const float4*)(p + i);
    m = fmaxf(m, fmaxf(fmaxf(fabsf(v.x), fabsf(v.y)), fmaxf(fabsf(v.z), fabsf(v.w))));
  }
  for (int o = 32; o; o >>= 1) m = fmaxf(m, __shfl_xor(m, o));
  __shared__ float sm[4];
  if ((threadIdx.x & 63) == 0) sm[threadIdx.x >> 6] = m;
  __syncthreads();
  if (threadIdx.x == 0) {
    m = fmaxf(fmaxf(sm[0], sm[1]), fmaxf(sm[2], sm[3]));
    atomicMax(slot, __float_as_uint(m));
  }
}

// ---------------- plain int8 quantization (weights) ----------------
__global__ void quant_k(const float* __restrict__ p, int8_t* __restrict__ q, long n,
                        const unsigned* __restrict__ slot) {
  float inv = 127.f / fmaxf(__uint_as_float(*slot), 1e-8f);
  long i = ((long)blockIdx.x * blockDim.x + threadIdx.x) * 4;
  long stride = (long)gridDim.x * blockDim.x * 4;
  for (; i < n; i += stride) {
    float4 v = *(const float4*)(p + i);
    int b0 = (int)fminf(fmaxf(rintf(v.x * inv), -127.f), 127.f);
    int b1 = (int)fminf(fmaxf(rintf(v.y * inv), -127.f), 127.f);
    int b2 = (int)fminf(fmaxf(rintf(v.z * inv), -127.f), 127.f);
    int b3 = (int)fminf(fmaxf(rintf(v.w * inv), -127.f), 127.f);
    int w = (b0 & 0xff) | ((b1 & 0xff) << 8) | ((b2 & 0xff) << 16) | ((b3 & 0xff) << 24);
    *(int*)(q + i) = w;
  }
}

// ---------------- transpose A[16][K] -> At[K][16] ----------------
__global__ void transpose_k(const float* __restrict__ A, float* __restrict__ At, int K) {
  int k = blockIdx.x * 256 + threadIdx.x;
  if (k < K) {
#pragma unroll
    for (int r = 0; r < 16; r++) At[(long)k * 16 + r] = A[(long)r * K + k];
  }
}

// ---------------- fused: quantize one row of X AND compute T[row][:] = 2 * X[row] @ At ----------------
// grid = M blocks, 256 threads. thread t: r = t&15, seg g = t>>4 of K/16 elems.
__global__ void quant_lora_k(const float* __restrict__ X, const float* __restrict__ At,
                             const unsigned* __restrict__ slot, int8_t* __restrict__ Q,
                             float* __restrict__ T, int K) {
  int row = blockIdx.x;
  int t = threadIdx.x;
  int r = t & 15, g = t >> 4;
  const float* xr = X + (long)row * K;
  float inv = 127.f / fmaxf(__uint_as_float(*slot), 1e-8f);

  // LoRA down-projection partial dot
  int seg = K >> 4;
  const float* xp = xr + g * seg;
  const float* ap = At + (long)(g * seg) * 16 + r;
  float acc = 0.f;
  for (int j = 0; j < seg; j++) acc = fmaf(xp[j], ap[(long)j * 16], acc);
  __shared__ float sm[16][16];
  sm[g][r] = acc;
  __syncthreads();
  if (t < 16) {
    float s = 0.f;
#pragma unroll
    for (int gg = 0; gg < 16; gg++) s += sm[gg][t];
    T[(long)row * 16 + t] = 2.0f * s;  // LORA_SCALE = alpha/r = 32/16 = 2
  }

  // quantize the row (vectorized)
  for (int i0 = t * 4; i0 < K; i0 += 1024) {
    float4 v = *(const float4*)(xr + i0);
    int b0 = (int)fminf(fmaxf(rintf(v.x * inv), -127.f), 127.f);
    int b1 = (int)fminf(fmaxf(rintf(v.y * inv), -127.f), 127.f);
    int b2 = (int)fminf(fmaxf(rintf(v.z * inv), -127.f), 127.f);
    int b3 = (int)fminf(fmaxf(rintf(v.w * inv), -127.f), 127.f);
    int w = (b0 & 0xff) | ((b1 & 0xff) << 8) | ((b2 & 0xff) << 16) | ((b3 & 0xff) << 24);
    *(int*)(Q + (long)row * K + i0) = w;
  }
}

// ---------------- int8 GEMM: C[M][N] = s * (Aq[M][K] @ Bq[N][K]^T) + bias + T@Bl^T (+GELU) ----------------
// 128x128 tile, BK=64, 256 threads (4 waves 2x2), mfma_i32_16x16x64_i8.
// LDS layout quadrant-major: [kq(4)][row(128)][16B] so frag ds_read_b128 is conflict-light.
template <bool GELU>
__global__ __launch_bounds__(256, 2) void gemm_q8(
    const int8_t* __restrict__ Aq, const int8_t* __restrict__ Bq,
    int M, int N, int K,
    const unsigned* __restrict__ sa, const unsigned* __restrict__ sb,
    const float* __restrict__ bias,
    const float* __restrict__ T,   // [M][16], pre-scaled by LORA_SCALE
    const float* __restrict__ Bl,  // [N][16]
    float* __restrict__ C, unsigned* hmax) {
  __shared__ __align__(16) int8_t As[8192];
  __shared__ __align__(16) int8_t Bs[8192];

  // bijective XCD swizzle (nwg % 8 == 0 for all our grids)
  int nwg = gridDim.x * gridDim.y;
  int lid = blockIdx.y * gridDim.x + blockIdx.x;
  int q8 = nwg >> 3;
  int nid = (lid & 7) * q8 + (lid >> 3);
  int bn = (nid % gridDim.x) * 128;
  int bm = (nid / gridDim.x) * 128;

  int t = threadIdx.x;
  int lane = t & 63, wave = t >> 6;
  int wr = wave >> 1, wc = wave & 1;
  int l16 = lane & 15, lq = lane >> 4;

  // staging map: linear LDS byte a=(it*256+t)*16 -> kq=a>>11, row=(a>>4)&127
  int a0 = t * 16, a1 = (256 + t) * 16;
  int kq0 = a0 >> 11, row0 = (a0 >> 4) & 127;
  int kq1 = a1 >> 11, row1 = (a1 >> 4) & 127;

  const int8_t* Abase = Aq + (long)bm * K;
  const int8_t* Bbase = Bq + (long)bn * K;
  const int8_t* srcA0 = Abase + (long)row0 * K + kq0 * 16;
  const int8_t* srcA1 = Abase + (long)row1 * K + kq1 * 16;
  const int8_t* srcB0 = Bbase + (long)row0 * K + kq0 * 16;
  const int8_t* srcB1 = Bbase + (long)row1 * K + kq1 * 16;

  i32x4 acc[4][4] = {};

  int KT = K >> 6;
  for (int kt = 0; kt < KT; kt++) {
    long koff = (long)kt * 64;
    async_lds16(As + a0, srcA0 + koff);
    async_lds16(As + a1, srcA1 + koff);
    async_lds16(Bs + a0, srcB0 + koff);
    async_lds16(Bs + a1, srcB1 + koff);
    __syncthreads();  // drains vmcnt -> LDS tiles visible

    i32x4 av[4], bv[4];
#pragma unroll
    for (int mf = 0; mf < 4; mf++)
      av[mf] = *(const i32x4*)(As + lq * 2048 + (wr * 64 + mf * 16 + l16) * 16);
#pragma unroll
    for (int nf = 0; nf < 4; nf++)
      bv[nf] = *(const i32x4*)(Bs + lq * 2048 + (wc * 64 + nf * 16 + l16) * 16);
#pragma unroll
    for (int mf = 0; mf < 4; mf++)
#pragma unroll
      for (int nf = 0; nf < 4; nf++)
        acc[mf][nf] = __builtin_amdgcn_mfma_i32_16x16x64_i8(av[mf], bv[nf], acc[mf][nf], 0, 0, 0);
    __syncthreads();  // all waves done reading before next overwrite
  }

  // -------- epilogue --------
  float s = (fmaxf(__uint_as_float(*sa), 1e-8f) * (1.f / 127.f)) *
            (fmaxf(__uint_as_float(*sb), 1e-8f) * (1.f / 127.f));

  // LoRA-up fragments (fp32 -> f16; K=16 rank fits one 16x16x16 f16 MFMA)
  f16x4 af[4], bf[4];
#pragma unroll
  for (int mf = 0; mf < 4; mf++) {
    int m = bm + wr * 64 + mf * 16 + l16;
    float4 tv = *(const float4*)(T + (long)m * 16 + lq * 4);
    f16x4 v; v[0] = (_Float16)tv.x; v[1] = (_Float16)tv.y; v[2] = (_Float16)tv.z; v[3] = (_Float16)tv.w;
    af[mf] = v;
  }
#pragma unroll
  for (int nf = 0; nf < 4; nf++) {
    int n = bn + wc * 64 + nf * 16 + l16;
    float4 bv4 = *(const float4*)(Bl + (long)n * 16 + lq * 4);
    f16x4 v; v[0] = (_Float16)bv4.x; v[1] = (_Float16)bv4.y; v[2] = (_Float16)bv4.z; v[3] = (_Float16)bv4.w;
    bf[nf] = v;
  }
  float bias_v[4];
#pragma unroll
  for (int nf = 0; nf < 4; nf++) bias_v[nf] = bias[bn + wc * 64 + nf * 16 + l16];

  float lmax = 0.f;
#pragma unroll
  for (int mf = 0; mf < 4; mf++) {
#pragma unroll
    for (int nf = 0; nf < 4; nf++) {
      f32x4 fa = __builtin_amdgcn_mfma_f32_16x16x16f16(af[mf], bf[nf], f32x4{0.f, 0.f, 0.f, 0.f}, 0, 0, 0);
      int n = bn + wc * 64 + nf * 16 + l16;
#pragma unroll
      for (int j = 0; j < 4; j++) {
        int m = bm + wr * 64 + mf * 16 + lq * 4 + j;
        float v = s * (float)acc[mf][nf][j] + bias_v[nf] + fa[j];
        if constexpr (GELU) {
          v = 0.5f * v * (1.0f + erff(v * 0.70710678118654752f));
          lmax = fmaxf(lmax, fabsf(v));
        }
        C[(long)m * N + n] = v;
      }
    }
  }
  if constexpr (GELU) {
    for (int o = 32; o; o >>= 1) lmax = fmaxf(lmax, __shfl_xor(lmax, o));
    if (lane == 0) atomicMax(hmax, __float_as_uint(lmax));
  }
}

// ---------------- launch ----------------
extern "C" void kernel_launch(void* const* d_in, const int* in_sizes, int n_in,
                              void* d_out, int out_size, void* d_ws, size_t ws_size,
                              hipStream_t stream) {
  const float* x   = (const float*)d_in[0];
  const float* Wfc = (const float*)d_in[1];
  const float* bfc = (const float*)d_in[2];
  const float* Afc = (const float*)d_in[3];
  const float* Bfc = (const float*)d_in[4];
  const float* Wpj = (const float*)d_in[5];
  const float* bpj = (const float*)d_in[6];
  const float* Apj = (const float*)d_in[7];
  const float* Bpj = (const float*)d_in[8];
  float* out = (float*)d_out;

  char* ws = (char*)d_ws;
  unsigned* slots = (unsigned*)ws;  // [0]=max|x| [1]=max|Wfc| [2]=max|Wpj| [3]=max|h|
  int8_t* qx  = (int8_t*)(ws + 256);
  int8_t* qwf = qx  + (size_t)M_TOK * N_EMB;
  int8_t* qwp = qwf + (size_t)D_FF * N_EMB;
  int8_t* qh  = qwp + (size_t)N_EMB * D_FF;
  float*  t1  = (float*)(qh + (size_t)M_TOK * D_FF);
  float*  t2  = t1  + (size_t)M_TOK * 16;
  float*  At1 = t2  + (size_t)M_TOK * 16;
  float*  At2 = At1 + (size_t)N_EMB * 16;
  float*  h   = At2 + (size_t)D_FF * 16;

  zero_slots_k<<<1, 64, 0, stream>>>(slots);
  absmax_k<<<1024, 256, 0, stream>>>(x,   (long)M_TOK * N_EMB, slots + 0);
  absmax_k<<<1024, 256, 0, stream>>>(Wfc, (long)D_FF * N_EMB,  slots + 1);
  absmax_k<<<1024, 256, 0, stream>>>(Wpj, (long)N_EMB * D_FF,  slots + 2);

  quant_k<<<2048, 256, 0, stream>>>(Wfc, qwf, (long)D_FF * N_EMB, slots + 1);
  quant_k<<<2048, 256, 0, stream>>>(Wpj, qwp, (long)N_EMB * D_FF, slots + 2);

  transpose_k<<<4, 256, 0, stream>>>(Afc, At1, N_EMB);
  transpose_k<<<16, 256, 0, stream>>>(Apj, At2, D_FF);

  quant_lora_k<<<M_TOK, 256, 0, stream>>>(x, At1, slots + 0, qx, t1, N_EMB);

  gemm_q8<true><<<dim3(D_FF / 128, M_TOK / 128), 256, 0, stream>>>(
      qx, qwf, M_TOK, D_FF, N_EMB, slots + 0, slots + 1, bfc, t1, Bfc, h, slots + 3);

  quant_lora_k<<<M_TOK, 256, 0, stream>>>(h, At2, slots + 3, qh, t2, D_FF);

  gemm_q8<false><<<dim3(N_EMB / 128, M_TOK / 128), 256, 0, stream>>>(
      qh, qwp, M_TOK, N_EMB, D_FF, slots + 3, slots + 2, bpj, t2, Bpj, out, nullptr);
}

// Round 2
// 338.017 us; speedup vs baseline: 1.6220x; 1.6220x over previous
//
#include <hip/hip_runtime.h>
#include <stdint.h>

// ---------------- types ----------------
using i32x4 = __attribute__((ext_vector_type(4))) int;
using f32x4 = __attribute__((ext_vector_type(4))) float;
using f16x4 = __attribute__((ext_vector_type(4))) _Float16;

#define M_TOK 8192
#define N_EMB 1024
#define D_FF  4096

__device__ __forceinline__ void async_lds16(void* lds, const void* g) {
  __builtin_amdgcn_global_load_lds(
      (const __attribute__((address_space(1))) void*)g,
      (__attribute__((address_space(3))) void*)lds, 16, 0, 0);
}

// ---------------- tiny init ----------------
__global__ void zero_slots_k(unsigned* s) {
  if (threadIdx.x < 16) s[threadIdx.x] = 0u;
}

// ---------------- global absmax (float bits atomicMax, order-independent) ----------------
__global__ void absmax_k(const float* __restrict__ p, long n, unsigned* __restrict__ slot) {
  long i = ((long)blockIdx.x * blockDim.x + threadIdx.x) * 4;
  long stride = (long)gridDim.x * blockDim.x * 4;
  float m = 0.f;
  for (; i < n; i += stride) {
    float4 v = *(const float4*)(p + i);
    m = fmaxf(m, fmaxf(fmaxf(fabsf(v.x), fabsf(v.y)), fmaxf(fabsf(v.z), fabsf(v.w))));
  }
  for (int o = 32; o; o >>= 1) m = fmaxf(m, __shfl_xor(m, o));
  __shared__ float sm[4];
  if ((threadIdx.x & 63) == 0) sm[threadIdx.x >> 6] = m;
  __syncthreads();
  if (threadIdx.x == 0) {
    m = fmaxf(fmaxf(sm[0], sm[1]), fmaxf(sm[2], sm[3]));
    atomicMax(slot, __float_as_uint(m));
  }
}

// ---------------- plain int8 quantization (weights) ----------------
__global__ void quant_k(const float* __restrict__ p, int8_t* __restrict__ q, long n,
                        const unsigned* __restrict__ slot) {
  float inv = 127.f / fmaxf(__uint_as_float(*slot), 1e-8f);
  long i = ((long)blockIdx.x * blockDim.x + threadIdx.x) * 4;
  long stride = (long)gridDim.x * blockDim.x * 4;
  for (; i < n; i += stride) {
    float4 v = *(const float4*)(p + i);
    int b0 = (int)fminf(fmaxf(rintf(v.x * inv), -127.f), 127.f);
    int b1 = (int)fminf(fmaxf(rintf(v.y * inv), -127.f), 127.f);
    int b2 = (int)fminf(fmaxf(rintf(v.z * inv), -127.f), 127.f);
    int b3 = (int)fminf(fmaxf(rintf(v.w * inv), -127.f), 127.f);
    int w = (b0 & 0xff) | ((b1 & 0xff) << 8) | ((b2 & 0xff) << 16) | ((b3 & 0xff) << 24);
    *(int*)(q + i) = w;
  }
}

// ---------------- pre-swizzle LoRA-down A[16][K] into per-lane MFMA B-fragments ----------------
// B-frag for mfma_f32_16x16x16f16 at k-step s: lane l holds B[k=16s+4*(l>>4)+j][col=l&15]
// = A[l&15][16s+4*(l>>4)+j]. Stored as Bp[s*256 + l*4 + j] (f16) -> one 8B load per lane/step.
__global__ void prep_bfrag_k(const float* __restrict__ A, _Float16* __restrict__ Bp, int K) {
  int s = blockIdx.x;
  int l = threadIdx.x;  // 64 threads
  int r = l & 15, g = l >> 4;
  float4 v = *(const float4*)(A + (long)r * K + s * 16 + g * 4);
  f16x4 h;
  h[0] = (_Float16)v.x; h[1] = (_Float16)v.y; h[2] = (_Float16)v.z; h[3] = (_Float16)v.w;
  *(f16x4*)(Bp + ((long)s * 64 + l) * 4) = h;
}

// ---------------- fused: quantize X rows to int8 AND T = 2 * X @ A^T via f16 MFMA ----------------
// grid = M/16 blocks, 512 threads (8 waves). Wave w owns k-range [w*K/8, (w+1)*K/8) for the
// block's 16 rows. Per k-step: coalesced float4 x-load feeds BOTH int8 quant-store and the
// f16 A-fragment; B-fragment is one coalesced 8B load from the pre-swizzled panel.
__global__ __launch_bounds__(512) void lora_quant_k(
    const float* __restrict__ X, const _Float16* __restrict__ Bpre,
    const unsigned* __restrict__ slot, int8_t* __restrict__ Q,
    float* __restrict__ T, int K) {
  int lane = threadIdx.x & 63, wave = threadIdx.x >> 6;
  int row0 = blockIdx.x * 16;
  int r = lane & 15, g = lane >> 4;
  float inv = 127.f / fmaxf(__uint_as_float(*slot), 1e-8f);

  int kPerWave = K >> 3;
  int kbase = wave * kPerWave;
  const float* xrow = X + (long)(row0 + r) * K;
  int8_t* qrow = Q + (long)(row0 + r) * K;

  f32x4 acc = {0.f, 0.f, 0.f, 0.f};
  int nsteps = kPerWave >> 4;
#pragma unroll 4
  for (int s = 0; s < nsteps; s++) {
    int k = kbase + s * 16 + g * 4;
    float4 v = *(const float4*)(xrow + k);
    // quantize + pack + store (4 int8 as one int)
    int b0 = (int)fminf(fmaxf(rintf(v.x * inv), -127.f), 127.f);
    int b1 = (int)fminf(fmaxf(rintf(v.y * inv), -127.f), 127.f);
    int b2 = (int)fminf(fmaxf(rintf(v.z * inv), -127.f), 127.f);
    int b3 = (int)fminf(fmaxf(rintf(v.w * inv), -127.f), 127.f);
    *(int*)(qrow + k) = (b0 & 0xff) | ((b1 & 0xff) << 8) | ((b2 & 0xff) << 16) | ((b3 & 0xff) << 24);
    // f16 A-fragment
    f16x4 a;
    a[0] = (_Float16)v.x; a[1] = (_Float16)v.y; a[2] = (_Float16)v.z; a[3] = (_Float16)v.w;
    // pre-swizzled B-fragment (8B coalesced)
    int gs = (kbase + s * 16) >> 4;
    f16x4 b = *(const f16x4*)(Bpre + ((long)gs * 64 + lane) * 4);
    acc = __builtin_amdgcn_mfma_f32_16x16x16f16(a, b, acc, 0, 0, 0);
  }

  // cross-wave reduce: C lane mapping col=lane&15 (rank), row=(lane>>4)*4+j (x-row)
  __shared__ float part[8][16][17];
#pragma unroll
  for (int j = 0; j < 4; j++) part[wave][g * 4 + j][r] = acc[j];
  __syncthreads();
  int t = threadIdx.x;
  if (t < 256) {
    int m = t >> 4, rr = t & 15;
    float sum = 0.f;
#pragma unroll
    for (int w = 0; w < 8; w++) sum += part[w][m][rr];
    T[(long)(row0 + m) * 16 + rr] = 2.0f * sum;  // LORA_SCALE = 32/16 = 2
  }
}

// ---------------- int8 GEMM: C[M][N] = s * (Aq[M][K] @ Bq[N][K]^T) + bias + T@Bl^T (+GELU) ----------------
// 128x128 tile, BK=64, 256 threads (4 waves 2x2), mfma_i32_16x16x64_i8.
// LDS layout quadrant-major: [kq(4)][row(128)][16B] so frag ds_read_b128 is conflict-light.
template <bool GELU>
__global__ __launch_bounds__(256, 2) void gemm_q8(
    const int8_t* __restrict__ Aq, const int8_t* __restrict__ Bq,
    int M, int N, int K,
    const unsigned* __restrict__ sa, const unsigned* __restrict__ sb,
    const float* __restrict__ bias,
    const float* __restrict__ T,   // [M][16], pre-scaled by LORA_SCALE
    const float* __restrict__ Bl,  // [N][16]
    float* __restrict__ C, unsigned* hmax) {
  __shared__ __align__(16) int8_t As[8192];
  __shared__ __align__(16) int8_t Bs[8192];

  // bijective XCD swizzle (nwg % 8 == 0 for all our grids)
  int nwg = gridDim.x * gridDim.y;
  int lid = blockIdx.y * gridDim.x + blockIdx.x;
  int q8 = nwg >> 3;
  int nid = (lid & 7) * q8 + (lid >> 3);
  int bn = (nid % gridDim.x) * 128;
  int bm = (nid / gridDim.x) * 128;

  int t = threadIdx.x;
  int lane = t & 63, wave = t >> 6;
  int wr = wave >> 1, wc = wave & 1;
  int l16 = lane & 15, lq = lane >> 4;

  // staging map: linear LDS byte a=(it*256+t)*16 -> kq=a>>11, row=(a>>4)&127
  int a0 = t * 16, a1 = (256 + t) * 16;
  int kq0 = a0 >> 11, row0 = (a0 >> 4) & 127;
  int kq1 = a1 >> 11, row1 = (a1 >> 4) & 127;

  const int8_t* Abase = Aq + (long)bm * K;
  const int8_t* Bbase = Bq + (long)bn * K;
  const int8_t* srcA0 = Abase + (long)row0 * K + kq0 * 16;
  const int8_t* srcA1 = Abase + (long)row1 * K + kq1 * 16;
  const int8_t* srcB0 = Bbase + (long)row0 * K + kq0 * 16;
  const int8_t* srcB1 = Bbase + (long)row1 * K + kq1 * 16;

  i32x4 acc[4][4] = {};

  int KT = K >> 6;
  for (int kt = 0; kt < KT; kt++) {
    long koff = (long)kt * 64;
    async_lds16(As + a0, srcA0 + koff);
    async_lds16(As + a1, srcA1 + koff);
    async_lds16(Bs + a0, srcB0 + koff);
    async_lds16(Bs + a1, srcB1 + koff);
    __syncthreads();  // drains vmcnt -> LDS tiles visible

    i32x4 av[4], bv[4];
#pragma unroll
    for (int mf = 0; mf < 4; mf++)
      av[mf] = *(const i32x4*)(As + lq * 2048 + (wr * 64 + mf * 16 + l16) * 16);
#pragma unroll
    for (int nf = 0; nf < 4; nf++)
      bv[nf] = *(const i32x4*)(Bs + lq * 2048 + (wc * 64 + nf * 16 + l16) * 16);
#pragma unroll
    for (int mf = 0; mf < 4; mf++)
#pragma unroll
      for (int nf = 0; nf < 4; nf++)
        acc[mf][nf] = __builtin_amdgcn_mfma_i32_16x16x64_i8(av[mf], bv[nf], acc[mf][nf], 0, 0, 0);
    __syncthreads();  // all waves done reading before next overwrite
  }

  // -------- epilogue --------
  float s = (fmaxf(__uint_as_float(*sa), 1e-8f) * (1.f / 127.f)) *
            (fmaxf(__uint_as_float(*sb), 1e-8f) * (1.f / 127.f));

  // LoRA-up fragments (fp32 -> f16; rank-16 fits one 16x16x16 f16 MFMA)
  f16x4 af[4], bf[4];
#pragma unroll
  for (int mf = 0; mf < 4; mf++) {
    int m = bm + wr * 64 + mf * 16 + l16;
    float4 tv = *(const float4*)(T + (long)m * 16 + lq * 4);
    f16x4 v; v[0] = (_Float16)tv.x; v[1] = (_Float16)tv.y; v[2] = (_Float16)tv.z; v[3] = (_Float16)tv.w;
    af[mf] = v;
  }
#pragma unroll
  for (int nf = 0; nf < 4; nf++) {
    int n = bn + wc * 64 + nf * 16 + l16;
    float4 bv4 = *(const float4*)(Bl + (long)n * 16 + lq * 4);
    f16x4 v; v[0] = (_Float16)bv4.x; v[1] = (_Float16)bv4.y; v[2] = (_Float16)bv4.z; v[3] = (_Float16)bv4.w;
    bf[nf] = v;
  }
  float bias_v[4];
#pragma unroll
  for (int nf = 0; nf < 4; nf++) bias_v[nf] = bias[bn + wc * 64 + nf * 16 + l16];

  float lmax = 0.f;
#pragma unroll
  for (int mf = 0; mf < 4; mf++) {
#pragma unroll
    for (int nf = 0; nf < 4; nf++) {
      f32x4 fa = __builtin_amdgcn_mfma_f32_16x16x16f16(af[mf], bf[nf], f32x4{0.f, 0.f, 0.f, 0.f}, 0, 0, 0);
      int n = bn + wc * 64 + nf * 16 + l16;
#pragma unroll
      for (int j = 0; j < 4; j++) {
        int m = bm + wr * 64 + mf * 16 + lq * 4 + j;
        float v = s * (float)acc[mf][nf][j] + bias_v[nf] + fa[j];
        if constexpr (GELU) {
          v = 0.5f * v * (1.0f + erff(v * 0.70710678118654752f));
          lmax = fmaxf(lmax, fabsf(v));
        }
        C[(long)m * N + n] = v;
      }
    }
  }
  if constexpr (GELU) {
    for (int o = 32; o; o >>= 1) lmax = fmaxf(lmax, __shfl_xor(lmax, o));
    if (lane == 0) atomicMax(hmax, __float_as_uint(lmax));
  }
}

// ---------------- launch ----------------
extern "C" void kernel_launch(void* const* d_in, const int* in_sizes, int n_in,
                              void* d_out, int out_size, void* d_ws, size_t ws_size,
                              hipStream_t stream) {
  const float* x   = (const float*)d_in[0];
  const float* Wfc = (const float*)d_in[1];
  const float* bfc = (const float*)d_in[2];
  const float* Afc = (const float*)d_in[3];
  const float* Bfc = (const float*)d_in[4];
  const float* Wpj = (const float*)d_in[5];
  const float* bpj = (const float*)d_in[6];
  const float* Apj = (const float*)d_in[7];
  const float* Bpj = (const float*)d_in[8];
  float* out = (float*)d_out;

  char* ws = (char*)d_ws;
  unsigned* slots = (unsigned*)ws;  // [0]=max|x| [1]=max|Wfc| [2]=max|Wpj| [3]=max|h|
  int8_t* qx  = (int8_t*)(ws + 256);
  int8_t* qwf = qx  + (size_t)M_TOK * N_EMB;
  int8_t* qwp = qwf + (size_t)D_FF * N_EMB;
  int8_t* qh  = qwp + (size_t)N_EMB * D_FF;
  float*  t1  = (float*)(qh + (size_t)M_TOK * D_FF);
  float*  t2  = t1  + (size_t)M_TOK * 16;
  _Float16* Bp1 = (_Float16*)(t2 + (size_t)M_TOK * 16);
  _Float16* Bp2 = Bp1 + (size_t)N_EMB * 16;
  float*  h   = (float*)(Bp2 + (size_t)D_FF * 16);

  zero_slots_k<<<1, 64, 0, stream>>>(slots);
  absmax_k<<<1024, 256, 0, stream>>>(x,   (long)M_TOK * N_EMB, slots + 0);
  absmax_k<<<1024, 256, 0, stream>>>(Wfc, (long)D_FF * N_EMB,  slots + 1);
  absmax_k<<<1024, 256, 0, stream>>>(Wpj, (long)N_EMB * D_FF,  slots + 2);

  quant_k<<<2048, 256, 0, stream>>>(Wfc, qwf, (long)D_FF * N_EMB, slots + 1);
  quant_k<<<2048, 256, 0, stream>>>(Wpj, qwp, (long)N_EMB * D_FF, slots + 2);

  prep_bfrag_k<<<N_EMB / 16, 64, 0, stream>>>(Afc, Bp1, N_EMB);
  prep_bfrag_k<<<D_FF / 16, 64, 0, stream>>>(Apj, Bp2, D_FF);

  lora_quant_k<<<M_TOK / 16, 512, 0, stream>>>(x, Bp1, slots + 0, qx, t1, N_EMB);

  gemm_q8<true><<<dim3(D_FF / 128, M_TOK / 128), 256, 0, stream>>>(
      qx, qwf, M_TOK, D_FF, N_EMB, slots + 0, slots + 1, bfc, t1, Bfc, h, slots + 3);

  lora_quant_k<<<M_TOK / 16, 512, 0, stream>>>(h, Bp2, slots + 3, qh, t2, D_FF);

  gemm_q8<false><<<dim3(N_EMB / 128, M_TOK / 128), 256, 0, stream>>>(
      qh, qwp, M_TOK, N_EMB, D_FF, slots + 3, slots + 2, bpj, t2, Bpj, out, nullptr);
}

// Round 3
// 305.929 us; speedup vs baseline: 1.7921x; 1.1049x over previous
//
#include <hip/hip_runtime.h>
#include <stdint.h>

// ---------------- types ----------------
using i32x4 = __attribute__((ext_vector_type(4))) int;
using f32x4 = __attribute__((ext_vector_type(4))) float;
using f16x4 = __attribute__((ext_vector_type(4))) _Float16;

#define M_TOK 8192
#define N_EMB 1024
#define D_FF  4096

__device__ __forceinline__ void async_lds16(void* lds, const void* g) {
  __builtin_amdgcn_global_load_lds(
      (const __attribute__((address_space(1))) void*)g,
      (__attribute__((address_space(3))) void*)lds, 16, 0, 0);
}

// ---------------- tiny init ----------------
__global__ void zero_slots_k(unsigned* s) {
  if (threadIdx.x < 16) s[threadIdx.x] = 0u;
}

// ---------------- global absmax (float bits atomicMax, order-independent) ----------------
__global__ void absmax_k(const float* __restrict__ p, long n, unsigned* __restrict__ slot) {
  long i = ((long)blockIdx.x * blockDim.x + threadIdx.x) * 4;
  long stride = (long)gridDim.x * blockDim.x * 4;
  float m = 0.f;
  for (; i < n; i += stride) {
    float4 v = *(const float4*)(p + i);
    m = fmaxf(m, fmaxf(fmaxf(fabsf(v.x), fabsf(v.y)), fmaxf(fabsf(v.z), fabsf(v.w))));
  }
  for (int o = 32; o; o >>= 1) m = fmaxf(m, __shfl_xor(m, o));
  __shared__ float sm[4];
  if ((threadIdx.x & 63) == 0) sm[threadIdx.x >> 6] = m;
  __syncthreads();
  if (threadIdx.x == 0) {
    m = fmaxf(fmaxf(sm[0], sm[1]), fmaxf(sm[2], sm[3]));
    atomicMax(slot, __float_as_uint(m));
  }
}

// ---------------- plain int8 quantization (weights) ----------------
__global__ void quant_k(const float* __restrict__ p, int8_t* __restrict__ q, long n,
                        const unsigned* __restrict__ slot) {
  float inv = 127.f / fmaxf(__uint_as_float(*slot), 1e-8f);
  long i = ((long)blockIdx.x * blockDim.x + threadIdx.x) * 4;
  long stride = (long)gridDim.x * blockDim.x * 4;
  for (; i < n; i += stride) {
    float4 v = *(const float4*)(p + i);
    int b0 = (int)fminf(fmaxf(rintf(v.x * inv), -127.f), 127.f);
    int b1 = (int)fminf(fmaxf(rintf(v.y * inv), -127.f), 127.f);
    int b2 = (int)fminf(fmaxf(rintf(v.z * inv), -127.f), 127.f);
    int b3 = (int)fminf(fmaxf(rintf(v.w * inv), -127.f), 127.f);
    int w = (b0 & 0xff) | ((b1 & 0xff) << 8) | ((b2 & 0xff) << 16) | ((b3 & 0xff) << 24);
    *(int*)(q + i) = w;
  }
}

// ---------------- pre-swizzle LoRA-down A[16][K] into per-lane MFMA B-fragments ----------------
__global__ void prep_bfrag_k(const float* __restrict__ A, _Float16* __restrict__ Bp, int K) {
  int s = blockIdx.x;
  int l = threadIdx.x;  // 64 threads
  int r = l & 15, g = l >> 4;
  float4 v = *(const float4*)(A + (long)r * K + s * 16 + g * 4);
  f16x4 h;
  h[0] = (_Float16)v.x; h[1] = (_Float16)v.y; h[2] = (_Float16)v.z; h[3] = (_Float16)v.w;
  *(f16x4*)(Bp + ((long)s * 64 + l) * 4) = h;
}

// ---------------- fused: quantize X rows to int8 AND T = 2 * X @ A^T via f16 MFMA ----------------
__global__ __launch_bounds__(512) void lora_quant_k(
    const float* __restrict__ X, const _Float16* __restrict__ Bpre,
    const unsigned* __restrict__ slot, int8_t* __restrict__ Q,
    float* __restrict__ T, int K) {
  int lane = threadIdx.x & 63, wave = threadIdx.x >> 6;
  int row0 = blockIdx.x * 16;
  int r = lane & 15, g = lane >> 4;
  float inv = 127.f / fmaxf(__uint_as_float(*slot), 1e-8f);

  int kPerWave = K >> 3;
  int kbase = wave * kPerWave;
  const float* xrow = X + (long)(row0 + r) * K;
  int8_t* qrow = Q + (long)(row0 + r) * K;

  f32x4 acc = {0.f, 0.f, 0.f, 0.f};
  int nsteps = kPerWave >> 4;
#pragma unroll 4
  for (int s = 0; s < nsteps; s++) {
    int k = kbase + s * 16 + g * 4;
    float4 v = *(const float4*)(xrow + k);
    int b0 = (int)fminf(fmaxf(rintf(v.x * inv), -127.f), 127.f);
    int b1 = (int)fminf(fmaxf(rintf(v.y * inv), -127.f), 127.f);
    int b2 = (int)fminf(fmaxf(rintf(v.z * inv), -127.f), 127.f);
    int b3 = (int)fminf(fmaxf(rintf(v.w * inv), -127.f), 127.f);
    *(int*)(qrow + k) = (b0 & 0xff) | ((b1 & 0xff) << 8) | ((b2 & 0xff) << 16) | ((b3 & 0xff) << 24);
    f16x4 a;
    a[0] = (_Float16)v.x; a[1] = (_Float16)v.y; a[2] = (_Float16)v.z; a[3] = (_Float16)v.w;
    int gs = (kbase + s * 16) >> 4;
    f16x4 b = *(const f16x4*)(Bpre + ((long)gs * 64 + lane) * 4);
    acc = __builtin_amdgcn_mfma_f32_16x16x16f16(a, b, acc, 0, 0, 0);
  }

  __shared__ float part[8][16][17];
#pragma unroll
  for (int j = 0; j < 4; j++) part[wave][g * 4 + j][r] = acc[j];
  __syncthreads();
  int t = threadIdx.x;
  if (t < 256) {
    int m = t >> 4, rr = t & 15;
    float sum = 0.f;
#pragma unroll
    for (int w = 0; w < 8; w++) sum += part[w][m][rr];
    T[(long)(row0 + m) * 16 + rr] = 2.0f * sum;  // LORA_SCALE = 32/16 = 2
  }
}

// ---------------- int8 GEMM: C = s*(Aq@Bq^T) + bias + T@Bl^T (+GELU) ----------------
// 128x128 tile, BK=128, 4 waves (2x2), mfma_i32_16x16x64_i8, 2-phase dbuf prefetch.
// LDS tile per matrix: [128 rows][8 x 16B slots], XOR-swizzled: slot c of row r lives at
// LDS byte r*128 + (c^(r&7))*16. Staged via linear-dest global_load_lds with the INVERSE
// permutation applied to the per-lane GLOBAL source (m173/m201 pattern); fragment reads
// apply the same XOR -> bank-conflict-free, and staged loads are 8x128B contiguous segments.
template <bool GELU>
__global__ __launch_bounds__(256, 2) void gemm_q8(
    const int8_t* __restrict__ Aq, const int8_t* __restrict__ Bq,
    int M, int N, int K,
    const unsigned* __restrict__ sa, const unsigned* __restrict__ sb,
    const float* __restrict__ bias,
    const float* __restrict__ T,   // [M][16], pre-scaled by LORA_SCALE
    const float* __restrict__ Bl,  // [N][16]
    float* __restrict__ C, unsigned* hmax) {
  __shared__ __align__(16) int8_t lds[65536];  // [buf][A 16K | B 16K]

  // bijective XCD swizzle (nwg % 8 == 0 for all our grids)
  int nwg = gridDim.x * gridDim.y;
  int lid = blockIdx.y * gridDim.x + blockIdx.x;
  int q8 = nwg >> 3;
  int nid = (lid & 7) * q8 + (lid >> 3);
  int bn = (nid % gridDim.x) * 128;
  int bm = (nid / gridDim.x) * 128;

  int t = threadIdx.x;
  int lane = t & 63, wave = t >> 6;
  int wr = wave >> 1, wc = wave & 1;
  int l16 = lane & 15, lq = lane >> 4;

  // staging: dest slot s = i*256+t (16B units); row = s>>3, lds col = t&7,
  // global col = (t&7) ^ (row&7)
  int ldst[4];
  const int8_t* srcA[4];
  const int8_t* srcB[4];
#pragma unroll
  for (int i = 0; i < 4; i++) {
    int s = i * 256 + t;
    int row = s >> 3;
    int cg = (t & 7) ^ (row & 7);
    ldst[i] = s * 16;
    srcA[i] = Aq + (long)(bm + row) * K + cg * 16;
    srcB[i] = Bq + (long)(bn + row) * K + cg * 16;
  }

  // fragment read byte-offsets (swizzled)
  int aoff[4][2], boff[4][2];
#pragma unroll
  for (int mf = 0; mf < 4; mf++) {
    int row = wr * 64 + mf * 16 + l16;
#pragma unroll
    for (int kh = 0; kh < 2; kh++) {
      int c = kh * 4 + lq;
      aoff[mf][kh] = row * 128 + ((c ^ (row & 7)) << 4);
    }
  }
#pragma unroll
  for (int nf = 0; nf < 4; nf++) {
    int row = wc * 64 + nf * 16 + l16;
#pragma unroll
    for (int kh = 0; kh < 2; kh++) {
      int c = kh * 4 + lq;
      boff[nf][kh] = row * 128 + ((c ^ (row & 7)) << 4);
    }
  }

  i32x4 acc[4][4] = {};
  int KT = K >> 7;

  // prologue: stage tile 0 into buf 0
  {
#pragma unroll
    for (int i = 0; i < 4; i++) {
      async_lds16(lds + ldst[i], srcA[i]);
      async_lds16(lds + 16384 + ldst[i], srcB[i]);
    }
  }
  __syncthreads();

  int cur = 0;
  for (int kt = 0; kt < KT; kt++) {
    // prefetch next K-tile into the other buffer (hidden under this tile's compute)
    if (kt + 1 < KT) {
      long ko = (long)(kt + 1) * 128;
      const int8_t* A_l_next_dummy;  // (no-op; keeps structure clear)
      (void)A_l_next_dummy;
      int nb = (cur ^ 1) * 32768;
#pragma unroll
      for (int i = 0; i < 4; i++) {
        async_lds16(lds + nb + ldst[i], srcA[i] + ko);
        async_lds16(lds + nb + 16384 + ldst[i], srcB[i] + ko);
      }
    }

    const int8_t* A_l = lds + cur * 32768;
    const int8_t* B_l = A_l + 16384;
#pragma unroll
    for (int kh = 0; kh < 2; kh++) {
      i32x4 av[4], bv[4];
#pragma unroll
      for (int mf = 0; mf < 4; mf++) av[mf] = *(const i32x4*)(A_l + aoff[mf][kh]);
#pragma unroll
      for (int nf = 0; nf < 4; nf++) bv[nf] = *(const i32x4*)(B_l + boff[nf][kh]);
      __builtin_amdgcn_s_setprio(1);
#pragma unroll
      for (int mf = 0; mf < 4; mf++)
#pragma unroll
        for (int nf = 0; nf < 4; nf++)
          acc[mf][nf] = __builtin_amdgcn_mfma_i32_16x16x64_i8(av[mf], bv[nf], acc[mf][nf], 0, 0, 0);
      __builtin_amdgcn_s_setprio(0);
    }
    __syncthreads();  // drains this wave's prefetch (vmcnt 0) + all waves done reading cur
    cur ^= 1;
  }

  // -------- epilogue --------
  float s = (fmaxf(__uint_as_float(*sa), 1e-8f) * (1.f / 127.f)) *
            (fmaxf(__uint_as_float(*sb), 1e-8f) * (1.f / 127.f));

  f16x4 af[4], bf[4];
#pragma unroll
  for (int mf = 0; mf < 4; mf++) {
    int m = bm + wr * 64 + mf * 16 + l16;
    float4 tv = *(const float4*)(T + (long)m * 16 + lq * 4);
    f16x4 v; v[0] = (_Float16)tv.x; v[1] = (_Float16)tv.y; v[2] = (_Float16)tv.z; v[3] = (_Float16)tv.w;
    af[mf] = v;
  }
#pragma unroll
  for (int nf = 0; nf < 4; nf++) {
    int n = bn + wc * 64 + nf * 16 + l16;
    float4 bv4 = *(const float4*)(Bl + (long)n * 16 + lq * 4);
    f16x4 v; v[0] = (_Float16)bv4.x; v[1] = (_Float16)bv4.y; v[2] = (_Float16)bv4.z; v[3] = (_Float16)bv4.w;
    bf[nf] = v;
  }
  float bias_v[4];
#pragma unroll
  for (int nf = 0; nf < 4; nf++) bias_v[nf] = bias[bn + wc * 64 + nf * 16 + l16];

  float lmax = 0.f;
#pragma unroll
  for (int mf = 0; mf < 4; mf++) {
#pragma unroll
    for (int nf = 0; nf < 4; nf++) {
      f32x4 fa = __builtin_amdgcn_mfma_f32_16x16x16f16(af[mf], bf[nf], f32x4{0.f, 0.f, 0.f, 0.f}, 0, 0, 0);
      int n = bn + wc * 64 + nf * 16 + l16;
#pragma unroll
      for (int j = 0; j < 4; j++) {
        int m = bm + wr * 64 + mf * 16 + lq * 4 + j;
        float v = s * (float)acc[mf][nf][j] + bias_v[nf] + fa[j];
        if constexpr (GELU) {
          v = 0.5f * v * (1.0f + erff(v * 0.70710678118654752f));
          lmax = fmaxf(lmax, fabsf(v));
        }
        C[(long)m * N + n] = v;
      }
    }
  }
  if constexpr (GELU) {
    for (int o = 32; o; o >>= 1) lmax = fmaxf(lmax, __shfl_xor(lmax, o));
    if (lane == 0) atomicMax(hmax, __float_as_uint(lmax));
  }
}

// ---------------- launch ----------------
extern "C" void kernel_launch(void* const* d_in, const int* in_sizes, int n_in,
                              void* d_out, int out_size, void* d_ws, size_t ws_size,
                              hipStream_t stream) {
  const float* x   = (const float*)d_in[0];
  const float* Wfc = (const float*)d_in[1];
  const float* bfc = (const float*)d_in[2];
  const float* Afc = (const float*)d_in[3];
  const float* Bfc = (const float*)d_in[4];
  const float* Wpj = (const float*)d_in[5];
  const float* bpj = (const float*)d_in[6];
  const float* Apj = (const float*)d_in[7];
  const float* Bpj = (const float*)d_in[8];
  float* out = (float*)d_out;

  char* ws = (char*)d_ws;
  unsigned* slots = (unsigned*)ws;  // [0]=max|x| [1]=max|Wfc| [2]=max|Wpj| [3]=max|h|
  int8_t* qx  = (int8_t*)(ws + 256);
  int8_t* qwf = qx  + (size_t)M_TOK * N_EMB;
  int8_t* qwp = qwf + (size_t)D_FF * N_EMB;
  int8_t* qh  = qwp + (size_t)N_EMB * D_FF;
  float*  t1  = (float*)(qh + (size_t)M_TOK * D_FF);
  float*  t2  = t1  + (size_t)M_TOK * 16;
  _Float16* Bp1 = (_Float16*)(t2 + (size_t)M_TOK * 16);
  _Float16* Bp2 = Bp1 + (size_t)N_EMB * 16;
  float*  h   = (float*)(Bp2 + (size_t)D_FF * 16);

  zero_slots_k<<<1, 64, 0, stream>>>(slots);
  absmax_k<<<1024, 256, 0, stream>>>(x,   (long)M_TOK * N_EMB, slots + 0);
  absmax_k<<<1024, 256, 0, stream>>>(Wfc, (long)D_FF * N_EMB,  slots + 1);
  absmax_k<<<1024, 256, 0, stream>>>(Wpj, (long)N_EMB * D_FF,  slots + 2);

  quant_k<<<2048, 256, 0, stream>>>(Wfc, qwf, (long)D_FF * N_EMB, slots + 1);
  quant_k<<<2048, 256, 0, stream>>>(Wpj, qwp, (long)N_EMB * D_FF, slots + 2);

  prep_bfrag_k<<<N_EMB / 16, 64, 0, stream>>>(Afc, Bp1, N_EMB);
  prep_bfrag_k<<<D_FF / 16, 64, 0, stream>>>(Apj, Bp2, D_FF);

  lora_quant_k<<<M_TOK / 16, 512, 0, stream>>>(x, Bp1, slots + 0, qx, t1, N_EMB);

  gemm_q8<true><<<dim3(D_FF / 128, M_TOK / 128), 256, 0, stream>>>(
      qx, qwf, M_TOK, D_FF, N_EMB, slots + 0, slots + 1, bfc, t1, Bfc, h, slots + 3);

  lora_quant_k<<<M_TOK / 16, 512, 0, stream>>>(h, Bp2, slots + 3, qh, t2, D_FF);

  gemm_q8<false><<<dim3(N_EMB / 128, M_TOK / 128), 256, 0, stream>>>(
      qh, qwp, M_TOK, N_EMB, D_FF, slots + 3, slots + 2, bpj, t2, Bpj, out, nullptr);
}

// Round 4
// 301.647 us; speedup vs baseline: 1.8175x; 1.0142x over previous
//
#include <hip/hip_runtime.h>
#include <stdint.h>

// ---------------- types ----------------
using i32x4 = __attribute__((ext_vector_type(4))) int;
using f32x4 = __attribute__((ext_vector_type(4))) float;
using f16x4 = __attribute__((ext_vector_type(4))) _Float16;

#define M_TOK 8192
#define N_EMB 1024
#define D_FF  4096

__device__ __forceinline__ void async_lds16(void* lds, const void* g) {
  __builtin_amdgcn_global_load_lds(
      (const __attribute__((address_space(1))) void*)g,
      (__attribute__((address_space(3))) void*)lds, 16, 0, 0);
}

// ---------------- tiny init ----------------
__global__ void zero_slots_k(unsigned* s) {
  if (threadIdx.x < 16) s[threadIdx.x] = 0u;
}

// ---------------- global absmax (float bits atomicMax, order-independent) ----------------
__global__ void absmax_k(const float* __restrict__ p, long n, unsigned* __restrict__ slot) {
  long i = ((long)blockIdx.x * blockDim.x + threadIdx.x) * 4;
  long stride = (long)gridDim.x * blockDim.x * 4;
  float m = 0.f;
  for (; i < n; i += stride) {
    float4 v = *(const float4*)(p + i);
    m = fmaxf(m, fmaxf(fmaxf(fabsf(v.x), fabsf(v.y)), fmaxf(fabsf(v.z), fabsf(v.w))));
  }
  for (int o = 32; o; o >>= 1) m = fmaxf(m, __shfl_xor(m, o));
  __shared__ float sm[4];
  if ((threadIdx.x & 63) == 0) sm[threadIdx.x >> 6] = m;
  __syncthreads();
  if (threadIdx.x == 0) {
    m = fmaxf(fmaxf(sm[0], sm[1]), fmaxf(sm[2], sm[3]));
    atomicMax(slot, __float_as_uint(m));
  }
}

// ---------------- plain int8 quantization (weights) ----------------
__global__ void quant_k(const float* __restrict__ p, int8_t* __restrict__ q, long n,
                        const unsigned* __restrict__ slot) {
  float inv = 127.f / fmaxf(__uint_as_float(*slot), 1e-8f);
  long i = ((long)blockIdx.x * blockDim.x + threadIdx.x) * 4;
  long stride = (long)gridDim.x * blockDim.x * 4;
  for (; i < n; i += stride) {
    float4 v = *(const float4*)(p + i);
    int b0 = (int)fminf(fmaxf(rintf(v.x * inv), -127.f), 127.f);
    int b1 = (int)fminf(fmaxf(rintf(v.y * inv), -127.f), 127.f);
    int b2 = (int)fminf(fmaxf(rintf(v.z * inv), -127.f), 127.f);
    int b3 = (int)fminf(fmaxf(rintf(v.w * inv), -127.f), 127.f);
    int w = (b0 & 0xff) | ((b1 & 0xff) << 8) | ((b2 & 0xff) << 16) | ((b3 & 0xff) << 24);
    *(int*)(q + i) = w;
  }
}

// ---------------- pre-swizzle LoRA-down A[16][K] into per-lane MFMA B-fragments ----------------
__global__ void prep_bfrag_k(const float* __restrict__ A, _Float16* __restrict__ Bp, int K) {
  int s = blockIdx.x;
  int l = threadIdx.x;  // 64 threads
  int r = l & 15, g = l >> 4;
  float4 v = *(const float4*)(A + (long)r * K + s * 16 + g * 4);
  f16x4 h;
  h[0] = (_Float16)v.x; h[1] = (_Float16)v.y; h[2] = (_Float16)v.z; h[3] = (_Float16)v.w;
  *(f16x4*)(Bp + ((long)s * 64 + l) * 4) = h;
}

// ---------------- fused: quantize X rows to int8 AND T = 2 * X @ A^T via f16 MFMA ----------------
__global__ __launch_bounds__(512) void lora_quant_k(
    const float* __restrict__ X, const _Float16* __restrict__ Bpre,
    const unsigned* __restrict__ slot, int8_t* __restrict__ Q,
    float* __restrict__ T, int K) {
  int lane = threadIdx.x & 63, wave = threadIdx.x >> 6;
  int row0 = blockIdx.x * 16;
  int r = lane & 15, g = lane >> 4;
  float inv = 127.f / fmaxf(__uint_as_float(*slot), 1e-8f);

  int kPerWave = K >> 3;
  int kbase = wave * kPerWave;
  const float* xrow = X + (long)(row0 + r) * K;
  int8_t* qrow = Q + (long)(row0 + r) * K;

  f32x4 acc = {0.f, 0.f, 0.f, 0.f};
  int nsteps = kPerWave >> 4;
#pragma unroll 4
  for (int s = 0; s < nsteps; s++) {
    int k = kbase + s * 16 + g * 4;
    float4 v = *(const float4*)(xrow + k);
    int b0 = (int)fminf(fmaxf(rintf(v.x * inv), -127.f), 127.f);
    int b1 = (int)fminf(fmaxf(rintf(v.y * inv), -127.f), 127.f);
    int b2 = (int)fminf(fmaxf(rintf(v.z * inv), -127.f), 127.f);
    int b3 = (int)fminf(fmaxf(rintf(v.w * inv), -127.f), 127.f);
    *(int*)(qrow + k) = (b0 & 0xff) | ((b1 & 0xff) << 8) | ((b2 & 0xff) << 16) | ((b3 & 0xff) << 24);
    f16x4 a;
    a[0] = (_Float16)v.x; a[1] = (_Float16)v.y; a[2] = (_Float16)v.z; a[3] = (_Float16)v.w;
    int gs = (kbase + s * 16) >> 4;
    f16x4 b = *(const f16x4*)(Bpre + ((long)gs * 64 + lane) * 4);
    acc = __builtin_amdgcn_mfma_f32_16x16x16f16(a, b, acc, 0, 0, 0);
  }

  __shared__ float part[8][16][17];
#pragma unroll
  for (int j = 0; j < 4; j++) part[wave][g * 4 + j][r] = acc[j];
  __syncthreads();
  int t = threadIdx.x;
  if (t < 256) {
    int m = t >> 4, rr = t & 15;
    float sum = 0.f;
#pragma unroll
    for (int w = 0; w < 8; w++) sum += part[w][m][rr];
    T[(long)(row0 + m) * 16 + rr] = 2.0f * sum;  // LORA_SCALE = 32/16 = 2
  }
}

// ---------------- int8 GEMM: C = s*(Aq@Bq^T) + bias + T@Bl^T (+GELU) ----------------
// BM=128, BN=256, BK=64, 512 threads (8 waves as 2M x 4N, per-wave 64x64 output).
// Tri-buffered LDS (3 x 24KB), depth-2 pipeline: during tile kt, issue loads for kt+2
// into buf (kt+2)%3; end-of-tile does s_waitcnt vmcnt(3) + RAW s_barrier so the 3
// in-flight loads cross the barrier (counted-vmcnt, T3/T4). Buffer (kt+2)%3 last held
// kt-1 whose readers all passed the previous barrier -> race-free.
// LDS tiles row-major [rows][64B]; frag ds_read_b128 is bank-balanced (16-row stride
// 64B = 16 banks -> 8 lanes per 4-bank group = LDS throughput minimum).
template <bool GELU>
__global__ __launch_bounds__(512, 4) void gemm_q8(
    const int8_t* __restrict__ Aq, const int8_t* __restrict__ Bq,
    int M, int N, int K,
    const unsigned* __restrict__ sa, const unsigned* __restrict__ sb,
    const float* __restrict__ bias,
    const float* __restrict__ T,   // [M][16], pre-scaled by LORA_SCALE
    const float* __restrict__ Bl,  // [N][16]
    float* __restrict__ C, unsigned* hmax) {
  __shared__ __align__(16) int8_t sm[73728];  // 3 bufs x (A 8KB | B 16KB)

  // bijective XCD swizzle (nwg % 8 == 0 for all our grids)
  int nwg = gridDim.x * gridDim.y;
  int lid = blockIdx.y * gridDim.x + blockIdx.x;
  int q8 = nwg >> 3;
  int nid = (lid & 7) * q8 + (lid >> 3);
  int bn = (nid % gridDim.x) * 256;
  int bm = (nid / gridDim.x) * 128;

  int t = threadIdx.x;
  int lane = t & 63, wave = t >> 6;
  int wr = wave >> 2, wc = wave & 3;     // 2 x 4 wave grid
  int l16 = lane & 15, lq = lane >> 4;

  // staging: A tile 128x64B = 8KB = 512 x 16B (1 load/thread, 4 lanes/row -> 64B segs)
  //          B tile 256x64B = 16KB (2 loads/thread)
  const int8_t* srcA0 = Aq + (long)(bm + (t >> 2)) * K + (t & 3) * 16;
  const int8_t* srcB0 = Bq + (long)(bn + (t >> 2)) * K + (t & 3) * 16;
  const int8_t* srcB1 = Bq + (long)(bn + ((512 + t) >> 2)) * K + (t & 3) * 16;
  int dA = t * 16;            // dest offset in A region
  int dB0 = t * 16;           // dest offsets in B region
  int dB1 = 8192 + t * 16;

  // fragment read offsets (relative to region bases)
  int aoff[4], boff[4];
#pragma unroll
  for (int mf = 0; mf < 4; mf++) aoff[mf] = (wr * 64 + mf * 16 + l16) * 64 + lq * 16;
#pragma unroll
  for (int nf = 0; nf < 4; nf++) boff[nf] = (wc * 64 + nf * 16 + l16) * 64 + lq * 16;

  i32x4 acc[4][4] = {};
  int KT = K >> 6;

  // prologue: stage tiles 0,1 into bufs 0,1
  async_lds16(sm + dA, srcA0);
  async_lds16(sm + 8192 + dB0, srcB0);
  async_lds16(sm + 8192 + dB1, srcB1);
  async_lds16(sm + 24576 + dA, srcA0 + 64);
  async_lds16(sm + 24576 + 8192 + dB0, srcB0 + 64);
  async_lds16(sm + 24576 + 8192 + dB1, srcB1 + 64);
  __syncthreads();

  for (int kt = 0; kt < KT; ++kt) {
    const int8_t* base = sm + (kt % 3) * 24576;
    if (kt + 2 < KT) {
      int8_t* nb = sm + ((kt + 2) % 3) * 24576;
      long ko = (long)(kt + 2) * 64;
      async_lds16(nb + dA, srcA0 + ko);
      async_lds16(nb + 8192 + dB0, srcB0 + ko);
      async_lds16(nb + 8192 + dB1, srcB1 + ko);
    }

    i32x4 av[4], bv[4];
#pragma unroll
    for (int nf = 0; nf < 4; nf++) bv[nf] = *(const i32x4*)(base + 8192 + boff[nf]);
#pragma unroll
    for (int mf = 0; mf < 4; mf++) av[mf] = *(const i32x4*)(base + aoff[mf]);

    __builtin_amdgcn_s_setprio(1);
#pragma unroll
    for (int mf = 0; mf < 4; mf++)
#pragma unroll
      for (int nf = 0; nf < 4; nf++)
        acc[mf][nf] = __builtin_amdgcn_mfma_i32_16x16x64_i8(av[mf], bv[nf], acc[mf][nf], 0, 0, 0);
    __builtin_amdgcn_s_setprio(0);

    if (kt + 1 < KT) {
      if (kt + 2 < KT) {
        asm volatile("s_waitcnt vmcnt(3)" ::: "memory");  // kt+1 landed; kt+2 in flight
      } else {
        asm volatile("s_waitcnt vmcnt(0)" ::: "memory");
      }
      __builtin_amdgcn_s_barrier();
      __builtin_amdgcn_sched_barrier(0);
    }
  }

  // -------- epilogue --------
  float s = (fmaxf(__uint_as_float(*sa), 1e-8f) * (1.f / 127.f)) *
            (fmaxf(__uint_as_float(*sb), 1e-8f) * (1.f / 127.f));

  f16x4 af[4], bf[4];
#pragma unroll
  for (int mf = 0; mf < 4; mf++) {
    int m = bm + wr * 64 + mf * 16 + l16;
    float4 tv = *(const float4*)(T + (long)m * 16 + lq * 4);
    f16x4 v; v[0] = (_Float16)tv.x; v[1] = (_Float16)tv.y; v[2] = (_Float16)tv.z; v[3] = (_Float16)tv.w;
    af[mf] = v;
  }
#pragma unroll
  for (int nf = 0; nf < 4; nf++) {
    int n = bn + wc * 64 + nf * 16 + l16;
    float4 bv4 = *(const float4*)(Bl + (long)n * 16 + lq * 4);
    f16x4 v; v[0] = (_Float16)bv4.x; v[1] = (_Float16)bv4.y; v[2] = (_Float16)bv4.z; v[3] = (_Float16)bv4.w;
    bf[nf] = v;
  }
  float bias_v[4];
#pragma unroll
  for (int nf = 0; nf < 4; nf++) bias_v[nf] = bias[bn + wc * 64 + nf * 16 + l16];

  float lmax = 0.f;
#pragma unroll
  for (int mf = 0; mf < 4; mf++) {
#pragma unroll
    for (int nf = 0; nf < 4; nf++) {
      f32x4 fa = __builtin_amdgcn_mfma_f32_16x16x16f16(af[mf], bf[nf], f32x4{0.f, 0.f, 0.f, 0.f}, 0, 0, 0);
      int n = bn + wc * 64 + nf * 16 + l16;
#pragma unroll
      for (int j = 0; j < 4; j++) {
        int m = bm + wr * 64 + mf * 16 + lq * 4 + j;
        float v = s * (float)acc[mf][nf][j] + bias_v[nf] + fa[j];
        if constexpr (GELU) {
          v = 0.5f * v * (1.0f + erff(v * 0.70710678118654752f));
          lmax = fmaxf(lmax, fabsf(v));
        }
        C[(long)m * N + n] = v;
      }
    }
  }
  if constexpr (GELU) {
    for (int o = 32; o; o >>= 1) lmax = fmaxf(lmax, __shfl_xor(lmax, o));
    if (lane == 0) atomicMax(hmax, __float_as_uint(lmax));
  }
}

// ---------------- launch ----------------
extern "C" void kernel_launch(void* const* d_in, const int* in_sizes, int n_in,
                              void* d_out, int out_size, void* d_ws, size_t ws_size,
                              hipStream_t stream) {
  const float* x   = (const float*)d_in[0];
  const float* Wfc = (const float*)d_in[1];
  const float* bfc = (const float*)d_in[2];
  const float* Afc = (const float*)d_in[3];
  const float* Bfc = (const float*)d_in[4];
  const float* Wpj = (const float*)d_in[5];
  const float* bpj = (const float*)d_in[6];
  const float* Apj = (const float*)d_in[7];
  const float* Bpj = (const float*)d_in[8];
  float* out = (float*)d_out;

  char* ws = (char*)d_ws;
  unsigned* slots = (unsigned*)ws;  // [0]=max|x| [1]=max|Wfc| [2]=max|Wpj| [3]=max|h|
  int8_t* qx  = (int8_t*)(ws + 256);
  int8_t* qwf = qx  + (size_t)M_TOK * N_EMB;
  int8_t* qwp = qwf + (size_t)D_FF * N_EMB;
  int8_t* qh  = qwp + (size_t)N_EMB * D_FF;
  float*  t1  = (float*)(qh + (size_t)M_TOK * D_FF);
  float*  t2  = t1  + (size_t)M_TOK * 16;
  _Float16* Bp1 = (_Float16*)(t2 + (size_t)M_TOK * 16);
  _Float16* Bp2 = Bp1 + (size_t)N_EMB * 16;
  float*  h   = (float*)(Bp2 + (size_t)D_FF * 16);

  zero_slots_k<<<1, 64, 0, stream>>>(slots);
  absmax_k<<<1024, 256, 0, stream>>>(x,   (long)M_TOK * N_EMB, slots + 0);
  absmax_k<<<1024, 256, 0, stream>>>(Wfc, (long)D_FF * N_EMB,  slots + 1);
  absmax_k<<<1024, 256, 0, stream>>>(Wpj, (long)N_EMB * D_FF,  slots + 2);

  quant_k<<<2048, 256, 0, stream>>>(Wfc, qwf, (long)D_FF * N_EMB, slots + 1);
  quant_k<<<2048, 256, 0, stream>>>(Wpj, qwp, (long)N_EMB * D_FF, slots + 2);

  prep_bfrag_k<<<N_EMB / 16, 64, 0, stream>>>(Afc, Bp1, N_EMB);
  prep_bfrag_k<<<D_FF / 16, 64, 0, stream>>>(Apj, Bp2, D_FF);

  lora_quant_k<<<M_TOK / 16, 512, 0, stream>>>(x, Bp1, slots + 0, qx, t1, N_EMB);

  gemm_q8<true><<<dim3(D_FF / 256, M_TOK / 128), 512, 0, stream>>>(
      qx, qwf, M_TOK, D_FF, N_EMB, slots + 0, slots + 1, bfc, t1, Bfc, h, slots + 3);

  lora_quant_k<<<M_TOK / 16, 512, 0, stream>>>(h, Bp2, slots + 3, qh, t2, D_FF);

  gemm_q8<false><<<dim3(N_EMB / 256, M_TOK / 128), 512, 0, stream>>>(
      qh, qwp, M_TOK, N_EMB, D_FF, slots + 3, slots + 2, bpj, t2, Bpj, out, nullptr);
}